// Round 21
// baseline (477.680 us; speedup 1.0000x reference)
//
#include <hip/hip_runtime.h>

#define BATCH 4
#define CH    192
#define PLANE 65536

typedef unsigned short u16;
typedef unsigned char  u8;
typedef __bf16 bf16x8_t __attribute__((ext_vector_type(8)));
typedef unsigned short u16x8 __attribute__((ext_vector_type(8)));
typedef unsigned short u16x4 __attribute__((ext_vector_type(4)));
typedef float f32x4 __attribute__((ext_vector_type(4)));

__device__ __forceinline__ u16 f2bf(float f) {
  __bf16 h = (__bf16)f;
  return __builtin_bit_cast(u16, h);
}
__device__ __forceinline__ float bf2f(u16 h) {
  unsigned u = ((unsigned)h) << 16;
  return __builtin_bit_cast(float, u);
}
__device__ __forceinline__ f32x4 mfma16(u16x8 a, u16x8 b, f32x4 c) {
  return __builtin_amdgcn_mfma_f32_16x16x32_bf16(
      __builtin_bit_cast(bf16x8_t, a), __builtin_bit_cast(bf16x8_t, b), c, 0, 0, 0);
}

// ---- prep: window-partition raw x -> bf16 [wid][tok][192c] + stats1 partials ----
__global__ __launch_bounds__(256) void prep_kernel(
    const float* __restrict__ x, u16* __restrict__ xraw, float2* __restrict__ part1)
{
  __shared__ u16 tile[32*264];
  const int t = threadIdx.x;
  const int bid = blockIdx.x;
  const int cc = bid % 6;
  const int wh = (bid/6) % 32;
  const int b  = bid / 192;
  const int c0 = cc*32;
  const int ww = t >> 3, ax = t & 7;
  const int gx = (ww*8 + ax + 4) & 255;
  const int gxb = gx & ~3, gxr = gx & 3;
  const long wid = b*1024 + wh*32 + ww;

  const int scl = t >> 3, sseg = t & 7;
  float myS = 0.f, myQ = 0.f;

  for (int ay = 0; ay < 8; ++ay) {
    const int gy = (wh*8 + ay + 4) & 255;
    for (int it = 0; it < 8; ++it) {
      const int id = it*256 + t;
      const int cl = id >> 6;
      const int px = (id & 63) << 2;
      float4 v = *(const float4*)(x + (((long)(b*192+c0+cl)) << 16) + gy*256 + px);
      u16x4 pk;
      pk[0] = f2bf(v.x); pk[1] = f2bf(v.y); pk[2] = f2bf(v.z); pk[3] = f2bf(v.w);
      *(u16x4*)&tile[cl*264 + (px ^ ((cl&7)<<2))] = pk;
    }
    __syncthreads();
    {
      const int sw = (scl & 7) << 2;
      #pragma unroll
      for (int k = 0; k < 32; k += 4) {
        const int px = sseg*32 + k;
        u16x4 pv = *(const u16x4*)&tile[scl*264 + (px ^ sw)];
        float a0 = bf2f(pv[0]), a1 = bf2f(pv[1]), a2 = bf2f(pv[2]), a3 = bf2f(pv[3]);
        myS += a0 + a1 + a2 + a3;
        myQ += a0*a0 + a1*a1 + a2*a2 + a3*a3;
      }
    }
    u16* dst = xraw + wid*12288 + (ay*8+ax)*192 + c0;
    #pragma unroll
    for (int k = 0; k < 4; ++k) {
      u16x8 pk;
      #pragma unroll
      for (int e = 0; e < 8; ++e) {
        const int c = k*8 + e;
        pk[e] = tile[c*264 + (gxb ^ ((c&7)<<2)) + gxr];
      }
      *(u16x8*)(dst + k*8) = pk;
    }
    __syncthreads();
  }
  for (int off = 1; off < 8; off <<= 1) {
    myS += __shfl_xor(myS, off, 64);
    myQ += __shfl_xor(myQ, off, 64);
  }
  if (sseg == 0) {
    float2 pr = {myS, myQ};
    part1[((b*32 + wh)*6 + cc)*32 + scl] = pr;
  }
}

// ---- setup: weights->bf16, bias->u8, gamma/beta, statsR — one kernel ----
__global__ __launch_bounds__(256) void setup_kernel(
    const float* __restrict__ a, const float* __restrict__ b2,
    const float* __restrict__ rb, const float* __restrict__ cond,
    const float* __restrict__ fw, const float* __restrict__ fb,
    const float2* __restrict__ part1,
    u16* __restrict__ wa, u16* __restrict__ wb, u8* __restrict__ bq,
    float* __restrict__ gb, float* __restrict__ st)
{
  const int blk = blockIdx.x;
  if (blk < 432) {
    const int i = blk*256 + threadIdx.x;
    if (i < 576*192) wa[i] = f2bf(a[i]);
    if (i < 192*192) wb[i] = f2bf(b2[i]);
    if (i < 1350) {
      float v = fminf(fmaxf(rintf(rb[i]*128.f) + 128.f, 0.f), 255.f);
      bq[i] = (u8)v;
    }
  } else if (blk < 438) {
    const int i = (blk - 432)*256 + threadIdx.x;
    if (i >= BATCH*384) return;
    const int bb = i / 384, oc = i - bb*384;
    const float* cw = fw + oc*128;
    const float* cv = cond + bb*128;
    float s = fb[oc];
    for (int k = 0; k < 128; ++k) s += cv[k]*cw[k];
    gb[i] = s;
  } else {
    const int i = (blk - 438)*256 + threadIdx.x;
    if (i >= 768) return;
    const int b = i / 192, c = i % 192;
    const int cg = c >> 5, cl = c & 31;
    float s = 0.f, q = 0.f;
    for (int wh = 0; wh < 32; ++wh) {
      float2 v = part1[((b*32 + wh)*6 + cg)*32 + cl];
      s += v.x; q += v.y;
    }
    const float mean = s * (1.f/PLANE);
    const float var  = q * (1.f/PLANE) - mean*mean;
    st[i*2]   = mean;
    st[i*2+1] = rsqrtf(var + 1e-5f);
  }
}

// ---- fused window attention + residual epilogue (R18 structure + setprio) ----
// LDS: Xs [64][200] @0 (25600)        normalized X, later O
//      G  [64][136] @25600 (17408)    Q|K
//      Vt [64][72]  @43008 (9216)
//      Pout [192][72] @25600 (27648, aliases G+Vt after attention)
//      biasQ u8[1350] @52224
//      stpNp float2[216] @53576 (1728) (mean, rstd) PADDED: idx = c + (c>>3)
//      stpR float2[192] @55304 (1536)  (mean, 1/rstd)
//      Ps  u16[8][1024] @56848 (16384) private per-wave P scratch
__global__ __launch_bounds__(512, 4) void attn_kernel(
    const u16* __restrict__ xn, const u16* __restrict__ wq, const u16* __restrict__ wp,
    const float* __restrict__ qkvb, const float* __restrict__ projb,
    const u8* __restrict__ bq, const float* __restrict__ st,
    u16* __restrict__ pw, float2* __restrict__ part)
{
  __shared__ __attribute__((aligned(16))) unsigned char smem[73232];
  u16*    Xs    = (u16*)smem;
  u16*    G     = (u16*)(smem + 25600);
  u16*    Vt    = (u16*)(smem + 43008);
  u16*    Pout  = (u16*)(smem + 25600);
  u8*     biasQ = (u8*)(smem + 52224);
  float2* stpNp = (float2*)(smem + 53576);
  float2* stpR  = (float2*)(smem + 55304);
  u16*    Ps    = (u16*)(smem + 56848);

  const int t    = threadIdx.x;
  const int lane = t & 63;
  const int wave = t >> 6;
  const int arow = lane & 15;
  const int kgrp = lane >> 4;

  const int bid = blockIdx.x;
  const int wid = (bid & 7) * 512 + (bid >> 3);   // XCD-contiguous
  const int b   = wid >> 10;
  const int wh  = (wid >> 5) & 31;
  const int ww  = wid & 31;

  // ---- tables first (stage depends on stpNp) ----
  for (int i = t; i < 1350; i += 512) biasQ[i] = bq[i];
  if (t < 192) {
    const float mean = st[(b*192 + t)*2];
    const float rstd = st[(b*192 + t)*2 + 1];
    float2 n = {mean, rstd};
    float2 r = {mean, 1.0f / rstd};
    stpNp[t + (t >> 3)] = n;   // padded: bank-spread reads in stage
    stpR[t] = r;
  }
  __syncthreads();

  // ---- stage: raw bf16 copy + normalize -> Xs ----
  const u16* src = xn + (long)wid*12288;
  #pragma unroll
  for (int it = 0; it < 3; ++it) {
    const int id = it*512 + t;
    const int row = id/24, c8 = (id%24)*8;
    const int sbase = c8 + (c8 >> 3);
    u16x8 raw = *(const u16x8*)(src + id*8);
    u16x8 nrm;
    #pragma unroll
    for (int e = 0; e < 8; ++e) {
      float2 mr = stpNp[sbase + e];
      nrm[e] = f2bf((bf2f(raw[e]) - mr.x) * mr.y);
    }
    *(u16x8*)&Xs[row*200 + c8] = nrm;
  }
  __syncthreads();

  const int hh = wave >> 2;
  const int mt = wave & 3;
  const bool boundary = (wh == 31) || (ww == 31);
  u16x4 og[3][2];

  #pragma unroll
  for (int g = 0; g < 3; ++g) {
    // QKV slice GEMM: 12 ntiles over 8 waves
    for (int nt0 = wave; nt0 < 12; nt0 += 8) {
      f32x4 acc[4] = {{0,0,0,0},{0,0,0,0},{0,0,0,0},{0,0,0,0}};
      const int col = nt0*16 + arow;
      const int mat = col >> 6;                 // 0 Q, 1 K, 2 V
      const int ch  = mat*192 + g*64 + (col & 63);
      const u16* wrow = wq + ch*192 + kgrp*8;
      __builtin_amdgcn_s_setprio(1);
      #pragma unroll
      for (int ks = 0; ks < 6; ++ks) {
        u16x8 bfr = *(const u16x8*)(wrow + ks*32);
        #pragma unroll
        for (int m = 0; m < 4; ++m) {
          u16x8 af = *(const u16x8*)&Xs[(m*16+arow)*200 + ks*32 + kgrp*8];
          acc[m] = mfma16(af, bfr, acc[m]);
        }
      }
      __builtin_amdgcn_s_setprio(0);
      const float addb = qkvb[ch];
      if (mat == 2) {
        const int vc = col & 63;
        #pragma unroll
        for (int m = 0; m < 4; ++m) {
          u16x4 pk;
          #pragma unroll
          for (int r = 0; r < 4; ++r) pk[r] = f2bf(acc[m][r] + addb);
          *(u16x4*)&Vt[vc*72 + m*16 + kgrp*4] = pk;
        }
      } else {
        const float mult = (mat == 0) ? 0.17677669529663687f : 1.0f;
        const int gc = mat*64 + (col & 63);
        #pragma unroll
        for (int m = 0; m < 4; ++m)
          #pragma unroll
          for (int r = 0; r < 4; ++r)
            G[(m*16 + kgrp*4 + r)*136 + gc] = f2bf((acc[m][r] + addb)*mult);
      }
    }
    __syncthreads();

    // attention: one (hh,mt) task per wave
    const int hd = g*2 + hh;
    u16x8 qf = *(const u16x8*)&G[(mt*16+arow)*136 + hh*32 + kgrp*8];
    f32x4 sv[4];
    __builtin_amdgcn_s_setprio(1);
    #pragma unroll
    for (int nt = 0; nt < 4; ++nt) {
      u16x8 kf = *(const u16x8*)&G[(nt*16+arow)*136 + 64 + hh*32 + kgrp*8];
      f32x4 z = {0,0,0,0};
      sv[nt] = mfma16(qf, kf, z);
    }
    __builtin_amdgcn_s_setprio(0);
    // (no barrier: P scratch is private, G/Vt untouched until end-g barrier)

    int qj6[4];
    #pragma unroll
    for (int nt = 0; nt < 4; ++nt) {
      const int j = nt*16 + arow;
      qj6[nt] = ((j>>3)*15 + (j&7))*6;
    }
    float p[4][4];
    if (!boundary) {
      #pragma unroll
      for (int r = 0; r < 4; ++r) {
        const int i = mt*16 + kgrp*4 + r;
        const int qib = ((i>>3)*15 + (i&7) + 112)*6 + hd;
        #pragma unroll
        for (int nt = 0; nt < 4; ++nt)
          p[nt][r] = sv[nt][r] + (float)((int)biasQ[qib - qj6[nt]] - 128) * 0.0078125f;
      }
    } else {
      #pragma unroll
      for (int r = 0; r < 4; ++r) {
        const int i  = mt*16 + kgrp*4 + r;
        const int iy = i >> 3, ix = i & 7;
        const int qib = (iy*15 + ix + 112)*6 + hd;
        const int ri = ((wh==31) ? (iy<4?1:2) : 0)*3 + ((ww==31) ? (ix<4?1:2) : 0);
        #pragma unroll
        for (int nt = 0; nt < 4; ++nt) {
          const int j  = nt*16 + arow;
          const int jy = j >> 3, jx = j & 7;
          const int rj = ((wh==31) ? (jy<4?1:2) : 0)*3 + ((ww==31) ? (jx<4?1:2) : 0);
          float sc = sv[nt][r] + (float)((int)biasQ[qib - qj6[nt]] - 128) * 0.0078125f;
          if (ri != rj) sc -= 100.0f;
          p[nt][r] = sc;
        }
      }
    }
    // softmax without max-subtraction (|score| small; -100 mask underflows to 0)
    #pragma unroll
    for (int r = 0; r < 4; ++r) {
      float sum = 0.f;
      #pragma unroll
      for (int nt = 0; nt < 4; ++nt) { p[nt][r] = __expf(p[nt][r]); sum += p[nt][r]; }
      for (int off = 1; off < 16; off <<= 1) sum += __shfl_xor(sum, off, 64);
      const float inv = 1.0f / sum;
      #pragma unroll
      for (int nt = 0; nt < 4; ++nt) p[nt][r] *= inv;
    }
    // P -> col-rotated private per-wave scratch
    u16* myP = Ps + wave*1024;
    #pragma unroll
    for (int r = 0; r < 4; ++r) {
      const int i = kgrp*4 + r;
      #pragma unroll
      for (int nt = 0; nt < 4; ++nt) {
        const int j = nt*16 + arow;
        myP[i*64 + ((j + 8*i) & 63)] = f2bf(p[nt][r]);
      }
    }
    f32x4 oacc[2] = {{0,0,0,0},{0,0,0,0}};
    __builtin_amdgcn_s_setprio(1);
    #pragma unroll
    for (int ks = 0; ks < 2; ++ks) {
      u16x8 pf = *(const u16x8*)&myP[arow*64 + ((ks*32 + kgrp*8 + 8*arow) & 63)];
      #pragma unroll
      for (int nt = 0; nt < 2; ++nt) {
        u16x8 vf = *(const u16x8*)&Vt[(hh*32 + nt*16 + arow)*72 + ks*32 + kgrp*8];
        oacc[nt] = mfma16(pf, vf, oacc[nt]);
      }
    }
    __builtin_amdgcn_s_setprio(0);
    #pragma unroll
    for (int nt = 0; nt < 2; ++nt)
      #pragma unroll
      for (int r = 0; r < 4; ++r)
        og[g][nt][r] = f2bf(oacc[nt][r]);
    __syncthreads();   // end-g: next QKV overwrites G/Vt
  }

  // ---- capture raw residual (epilogue lane mapping) before O overwrites Xs ----
  u16x8 rawreg[3];
  #pragma unroll
  for (int it = 0; it < 3; ++it) {
    const int id = it*512 + t;
    const int c = id >> 3, tk8 = (id & 7)*8;
    const float2 mi = stpR[c];
    u16x8 rr;
    #pragma unroll
    for (int e = 0; e < 8; ++e) {
      float nv = bf2f(Xs[(tk8 + e)*200 + c]);
      rr[e] = f2bf(nv*mi.y + mi.x);
    }
    rawreg[it] = rr;
  }
  __syncthreads();

  // ---- O (regs) -> Xs ----
  #pragma unroll
  for (int g = 0; g < 3; ++g)
    #pragma unroll
    for (int nt = 0; nt < 2; ++nt) {
      const int colb = g*64 + hh*32 + nt*16 + arow;
      #pragma unroll
      for (int r = 0; r < 4; ++r)
        Xs[(mt*16 + kgrp*4 + r)*200 + colb] = og[g][nt][r];
    }
  __syncthreads();

  // ---- proj GEMM -> Pout [ch][tok] ----
  for (int nt0 = wave; nt0 < 12; nt0 += 8) {
    const int ch = nt0*16 + arow;
    const float pb = projb[ch];
    f32x4 acc[4];
    #pragma unroll
    for (int m = 0; m < 4; ++m) { f32x4 v = {pb,pb,pb,pb}; acc[m] = v; }
    const u16* wrow = wp + ch*192 + kgrp*8;
    __builtin_amdgcn_s_setprio(1);
    #pragma unroll
    for (int ks = 0; ks < 6; ++ks) {
      u16x8 bfr = *(const u16x8*)(wrow + ks*32);
      #pragma unroll
      for (int m = 0; m < 4; ++m) {
        u16x8 af = *(const u16x8*)&Xs[(m*16+arow)*200 + ks*32 + kgrp*8];
        acc[m] = mfma16(af, bfr, acc[m]);
      }
    }
    __builtin_amdgcn_s_setprio(0);
    #pragma unroll
    for (int m = 0; m < 4; ++m) {
      u16x4 pk;
      #pragma unroll
      for (int r = 0; r < 4; ++r) pk[r] = f2bf(acc[m][r]);
      *(u16x4*)&Pout[ch*72 + m*16 + kgrp*4] = pk;
    }
  }
  __syncthreads();

  // ---- epilogue: v = raw + proj -> pw [wid][c][64tok]; stats2 partials ----
  u16* dstw = pw + (long)wid*12288;
  #pragma unroll
  for (int it = 0; it < 3; ++it) {
    const int id = it*512 + t;
    const int c = id >> 3, tk8 = (id & 7)*8;
    u16x8 pv = *(const u16x8*)&Pout[c*72 + tk8];
    u16x8 rr = rawreg[it];
    u16x8 vb;
    float s = 0.f, q = 0.f;
    #pragma unroll
    for (int e = 0; e < 8; ++e) {
      float v = bf2f(rr[e]) + bf2f(pv[e]);
      vb[e] = f2bf(v);
      s += v; q += v*v;
    }
    *(u16x8*)(dstw + c*64 + tk8) = vb;
    s += __shfl_xor(s, 1, 64); q += __shfl_xor(q, 1, 64);
    s += __shfl_xor(s, 2, 64); q += __shfl_xor(q, 2, 64);
    s += __shfl_xor(s, 4, 64); q += __shfl_xor(q, 4, 64);
    if ((lane & 7) == 0) {
      float2 pr = {s, q};
      part[(long)wid*192 + c] = pr;
    }
  }
}

// ---- stats2: reduce per-window v partials -> (mean, rstd) ----
__global__ __launch_bounds__(256) void stats2_kernel(
    const float2* __restrict__ part, float2* __restrict__ st2f) {
  const int b = blockIdx.x / 12, cg = blockIdx.x % 12;
  const int cl = threadIdx.x & 15;
  const int w0 = threadIdx.x >> 4;
  const int c = cg*16 + cl;
  float s = 0.f, q = 0.f;
  for (int w = w0; w < 1024; w += 16) {
    float2 v = part[((long)(b*1024 + w))*192 + c];
    s += v.x; q += v.y;
  }
  s += __shfl_xor(s, 16, 64); q += __shfl_xor(q, 16, 64);
  s += __shfl_xor(s, 32, 64); q += __shfl_xor(q, 32, 64);
  __shared__ float2 aux[4][16];
  if ((threadIdx.x & 63) < 16) { float2 v = {s, q}; aux[threadIdx.x >> 6][cl] = v; }
  __syncthreads();
  if (threadIdx.x < 16) {
    float2 a0 = aux[0][cl], a1 = aux[1][cl], a2 = aux[2][cl], a3 = aux[3][cl];
    float S = a0.x + a1.x + a2.x + a3.x;
    float Q = a0.y + a1.y + a2.y + a3.y;
    float mean = S * (1.f/PLANE);
    float var  = Q * (1.f/PLANE) - mean*mean;
    float2 o = {mean, rsqrtf(var + 1e-5f)};
    st2f[b*192 + c] = o;
  }
}

// ---- final: out = v + FiLM(norm2(v)); one block per (b, wh-band, c-chunk) ----
__global__ __launch_bounds__(256) void final_kernel(
    const u16* __restrict__ pw, const float2* __restrict__ st2f,
    const float* __restrict__ gb, float* __restrict__ out)
{
  __shared__ u16 tile[32*264];
  const int t = threadIdx.x;
  const int bid = blockIdx.x;
  const int lin = (bid & 7)*96 + (bid >> 3);   // 768 blocks, XCD-contiguous
  const int cc = lin % 6;
  const int band = lin / 6;                    // 0..127
  const int wh = band & 31;
  const int b  = band >> 5;
  const int c0 = cc*32;

  const int ww = t >> 3, cq = t & 7;
  const long wid = b*1024 + wh*32 + ww;
  const u16* srcw = pw + wid*12288;
  const int g1 = ww*8 + 4, g2 = (ww*8 + 8) & 255;

  const int cl = t >> 3, seg = t & 7;
  const int c = c0 + cl;
  const float2 mr = st2f[b*192 + c];
  const float mean = mr.x, rstd = mr.y;
  const float gmm  = gb[b*384 + c];
  const float be   = gb[b*384 + 192 + c];
  const int swb = (cl & 7) << 2;

  for (int ay = 0; ay < 8; ++ay) {
    #pragma unroll
    for (int j = 0; j < 4; ++j) {
      const int ca = cq*4 + j;
      u16x8 v = *(const u16x8*)(srcw + (c0+ca)*64 + ay*8);
      const int sw = (ca & 7) << 2;
      u16x4 lo = {v[0],v[1],v[2],v[3]}, hi = {v[4],v[5],v[6],v[7]};
      *(u16x4*)&tile[ca*264 + (g1 ^ sw)] = lo;
      *(u16x4*)&tile[ca*264 + (g2 ^ sw)] = hi;
    }
    __syncthreads();

    const int gy = (wh*8 + ay + 4) & 255;
    const long base = (((long)(b*192 + c)) << 16) + gy*256 + seg*32;
    float* orow = out + base;
    #pragma unroll
    for (int q4 = 0; q4 < 32; q4 += 4) {
      const int px = seg*32 + q4;
      u16x4 pv = *(const u16x4*)&tile[cl*264 + (px ^ swb)];
      float4 o;
      float v0 = bf2f(pv[0]), v1 = bf2f(pv[1]), v2 = bf2f(pv[2]), v3 = bf2f(pv[3]);
      o.x = v0 + (v0 - mean)*rstd*gmm + be;
      o.y = v1 + (v1 - mean)*rstd*gmm + be;
      o.z = v2 + (v2 - mean)*rstd*gmm + be;
      o.w = v3 + (v3 - mean)*rstd*gmm + be;
      *(float4*)(orow + q4) = o;
    }
    __syncthreads();
  }
}

extern "C" void kernel_launch(void* const* d_in, const int* in_sizes, int n_in,
                              void* d_out, int out_size, void* d_ws, size_t ws_size,
                              hipStream_t stream) {
  const float* x      = (const float*)d_in[0];
  const float* cond   = (const float*)d_in[1];
  const float* qkv_w  = (const float*)d_in[2];
  const float* qkv_b  = (const float*)d_in[3];
  const float* proj_w = (const float*)d_in[4];
  const float* proj_b = (const float*)d_in[5];
  const float* relb   = (const float*)d_in[6];
  const float* film_w = (const float*)d_in[7];
  const float* film_b = (const float*)d_in[8];
  float* out = (float*)d_out;

  char* ws = (char*)d_ws;
  float*  stats1 = (float*)ws;                        // 768*2 f32
  float2* st2f   = (float2*)(ws + 6144);              // 768 float2
  float*  gb     = (float*)(ws + 12288);              // 4*384 f32
  u16*    wq     = (u16*)(ws + 18432);                // 576*192 bf16
  u16*    wp     = (u16*)(ws + 239616);               // 192*192 bf16
  u8*     bqq    = (u8*)(ws + 313344);                // 1350 u8
  u16*    xbuf   = (u16*)(ws + 362496);               // 4096*64*192 bf16 (raw xn -> v)
  float2* part   = (float2*)(ws + 362496 + 100663296);// 4096*192 float2
  float2* part1  = (float2*)(ws + 362496 + 100663296 + 6291456); // 4*32*6*32 float2

  prep_kernel<<<768, 256, 0, stream>>>(x, xbuf, part1);
  setup_kernel<<<441, 256, 0, stream>>>(qkv_w, proj_w, relb, cond, film_w, film_b,
                                        part1, wq, wp, bqq, gb, stats1);
  attn_kernel<<<4096, 512, 0, stream>>>(xbuf, wq, wp, qkv_b, proj_b, bqq, stats1, xbuf, part);
  stats2_kernel<<<48, 256, 0, stream>>>(part, st2f);
  final_kernel<<<768, 256, 0, stream>>>(xbuf, st2f, gb, out);
}

// Round 22
// 471.409 us; speedup vs baseline: 1.0133x; 1.0133x over previous
//
#include <hip/hip_runtime.h>

#define BATCH 4
#define CH    192
#define PLANE 65536

typedef unsigned short u16;
typedef unsigned char  u8;
typedef __bf16 bf16x8_t __attribute__((ext_vector_type(8)));
typedef unsigned short u16x8 __attribute__((ext_vector_type(8)));
typedef unsigned short u16x4 __attribute__((ext_vector_type(4)));
typedef float f32x4 __attribute__((ext_vector_type(4)));

__device__ __forceinline__ u16 f2bf(float f) {
  __bf16 h = (__bf16)f;
  return __builtin_bit_cast(u16, h);
}
__device__ __forceinline__ float bf2f(u16 h) {
  unsigned u = ((unsigned)h) << 16;
  return __builtin_bit_cast(float, u);
}
__device__ __forceinline__ f32x4 mfma16(u16x8 a, u16x8 b, f32x4 c) {
  return __builtin_amdgcn_mfma_f32_16x16x32_bf16(
      __builtin_bit_cast(bf16x8_t, a), __builtin_bit_cast(bf16x8_t, b), c, 0, 0, 0);
}

// ---- prep: window-partition raw x -> bf16 [wid][tok][192c] + stats1 partials ----
__global__ __launch_bounds__(256) void prep_kernel(
    const float* __restrict__ x, u16* __restrict__ xraw, float2* __restrict__ part1)
{
  __shared__ u16 tile[32*264];
  const int t = threadIdx.x;
  const int bid = blockIdx.x;
  const int cc = bid % 6;
  const int wh = (bid/6) % 32;
  const int b  = bid / 192;
  const int c0 = cc*32;
  const int ww = t >> 3, ax = t & 7;
  const int gx = (ww*8 + ax + 4) & 255;
  const int gxb = gx & ~3, gxr = gx & 3;
  const long wid = b*1024 + wh*32 + ww;

  const int scl = t >> 3, sseg = t & 7;
  float myS = 0.f, myQ = 0.f;

  for (int ay = 0; ay < 8; ++ay) {
    const int gy = (wh*8 + ay + 4) & 255;
    for (int it = 0; it < 8; ++it) {
      const int id = it*256 + t;
      const int cl = id >> 6;
      const int px = (id & 63) << 2;
      float4 v = *(const float4*)(x + (((long)(b*192+c0+cl)) << 16) + gy*256 + px);
      u16x4 pk;
      pk[0] = f2bf(v.x); pk[1] = f2bf(v.y); pk[2] = f2bf(v.z); pk[3] = f2bf(v.w);
      *(u16x4*)&tile[cl*264 + (px ^ ((cl&7)<<2))] = pk;
    }
    __syncthreads();
    {
      const int sw = (scl & 7) << 2;
      #pragma unroll
      for (int k = 0; k < 32; k += 4) {
        const int px = sseg*32 + k;
        u16x4 pv = *(const u16x4*)&tile[scl*264 + (px ^ sw)];
        float a0 = bf2f(pv[0]), a1 = bf2f(pv[1]), a2 = bf2f(pv[2]), a3 = bf2f(pv[3]);
        myS += a0 + a1 + a2 + a3;
        myQ += a0*a0 + a1*a1 + a2*a2 + a3*a3;
      }
    }
    u16* dst = xraw + wid*12288 + (ay*8+ax)*192 + c0;
    #pragma unroll
    for (int k = 0; k < 4; ++k) {
      u16x8 pk;
      #pragma unroll
      for (int e = 0; e < 8; ++e) {
        const int c = k*8 + e;
        pk[e] = tile[c*264 + (gxb ^ ((c&7)<<2)) + gxr];
      }
      *(u16x8*)(dst + k*8) = pk;
    }
    __syncthreads();
  }
  for (int off = 1; off < 8; off <<= 1) {
    myS += __shfl_xor(myS, off, 64);
    myQ += __shfl_xor(myQ, off, 64);
  }
  if (sseg == 0) {
    float2 pr = {myS, myQ};
    part1[((b*32 + wh)*6 + cc)*32 + scl] = pr;
  }
}

// ---- setup: weights->bf16, bias->u8, gamma/beta, statsR — one kernel ----
__global__ __launch_bounds__(256) void setup_kernel(
    const float* __restrict__ a, const float* __restrict__ b2,
    const float* __restrict__ rb, const float* __restrict__ cond,
    const float* __restrict__ fw, const float* __restrict__ fb,
    const float2* __restrict__ part1,
    u16* __restrict__ wa, u16* __restrict__ wb, u8* __restrict__ bq,
    float* __restrict__ gb, float* __restrict__ st)
{
  const int blk = blockIdx.x;
  if (blk < 432) {
    const int i = blk*256 + threadIdx.x;
    if (i < 576*192) wa[i] = f2bf(a[i]);
    if (i < 192*192) wb[i] = f2bf(b2[i]);
    if (i < 1350) {
      float v = fminf(fmaxf(rintf(rb[i]*128.f) + 128.f, 0.f), 255.f);
      bq[i] = (u8)v;
    }
  } else if (blk < 438) {
    const int i = (blk - 432)*256 + threadIdx.x;
    if (i >= BATCH*384) return;
    const int bb = i / 384, oc = i - bb*384;
    const float* cw = fw + oc*128;
    const float* cv = cond + bb*128;
    float s = fb[oc];
    for (int k = 0; k < 128; ++k) s += cv[k]*cw[k];
    gb[i] = s;
  } else {
    const int i = (blk - 438)*256 + threadIdx.x;
    if (i >= 768) return;
    const int b = i / 192, c = i % 192;
    const int cg = c >> 5, cl = c & 31;
    float s = 0.f, q = 0.f;
    for (int wh = 0; wh < 32; ++wh) {
      float2 v = part1[((b*32 + wh)*6 + cg)*32 + cl];
      s += v.x; q += v.y;
    }
    const float mean = s * (1.f/PLANE);
    const float var  = q * (1.f/PLANE) - mean*mean;
    st[i*2]   = mean;
    st[i*2+1] = rsqrtf(var + 1e-5f);
  }
}

// ---- fused window attention + residual epilogue ----
// LDS: Xs [64][200] @0 (25600)        normalized X, later O
//      G  [64][136] @25600 (17408)    Q|K
//      Vt [64][72]  @43008 (9216)
//      Pout [192][72] @25600 (27648, aliases G+Vt after attention)
//      biasQ u8[1350] @52224
//      stpNp float2[216] @53576 (1728) (mean, rstd) PADDED: idx = c + (c>>3)
//      stpR float2[192] @55304 (1536)  (mean, 1/rstd)
//      Ps  u16[8][16*72] @56848 (18432) private per-wave P scratch, stride 72
__global__ __launch_bounds__(512, 4) void attn_kernel(
    const u16* __restrict__ xn, const u16* __restrict__ wq, const u16* __restrict__ wp,
    const float* __restrict__ qkvb, const float* __restrict__ projb,
    const u8* __restrict__ bq, const float* __restrict__ st,
    u16* __restrict__ pw, float2* __restrict__ part)
{
  __shared__ __attribute__((aligned(16))) unsigned char smem[75280];
  u16*    Xs    = (u16*)smem;
  u16*    G     = (u16*)(smem + 25600);
  u16*    Vt    = (u16*)(smem + 43008);
  u16*    Pout  = (u16*)(smem + 25600);
  u8*     biasQ = (u8*)(smem + 52224);
  float2* stpNp = (float2*)(smem + 53576);
  float2* stpR  = (float2*)(smem + 55304);
  u16*    Ps    = (u16*)(smem + 56848);

  const int t    = threadIdx.x;
  const int lane = t & 63;
  const int wave = t >> 6;
  const int arow = lane & 15;
  const int kgrp = lane >> 4;

  const int bid = blockIdx.x;
  const int wid = (bid & 7) * 512 + (bid >> 3);   // XCD-contiguous
  const int b   = wid >> 10;
  const int wh  = (wid >> 5) & 31;
  const int ww  = wid & 31;

  // ---- tables first (stage depends on stpNp) ----
  for (int i = t; i < 1350; i += 512) biasQ[i] = bq[i];
  if (t < 192) {
    const float mean = st[(b*192 + t)*2];
    const float rstd = st[(b*192 + t)*2 + 1];
    float2 n = {mean, rstd};
    float2 r = {mean, 1.0f / rstd};
    stpNp[t + (t >> 3)] = n;   // padded: bank-spread reads in stage
    stpR[t] = r;
  }
  __syncthreads();

  // ---- stage: raw bf16 copy + normalize -> Xs ----
  const u16* src = xn + (long)wid*12288;
  #pragma unroll
  for (int it = 0; it < 3; ++it) {
    const int id = it*512 + t;
    const int row = id/24, c8 = (id%24)*8;
    const int sbase = c8 + (c8 >> 3);
    u16x8 raw = *(const u16x8*)(src + id*8);
    u16x8 nrm;
    #pragma unroll
    for (int e = 0; e < 8; ++e) {
      float2 mr = stpNp[sbase + e];
      nrm[e] = f2bf((bf2f(raw[e]) - mr.x) * mr.y);
    }
    *(u16x8*)&Xs[row*200 + c8] = nrm;
  }
  __syncthreads();

  const int hh = wave >> 2;
  const int mt = wave & 3;
  const bool boundary = (wh == 31) || (ww == 31);
  u16x4 og[3][2];

  #pragma unroll
  for (int g = 0; g < 3; ++g) {
    // QKV slice GEMM: 12 ntiles over 8 waves
    for (int nt0 = wave; nt0 < 12; nt0 += 8) {
      f32x4 acc[4] = {{0,0,0,0},{0,0,0,0},{0,0,0,0},{0,0,0,0}};
      const int col = nt0*16 + arow;
      const int mat = col >> 6;                 // 0 Q, 1 K, 2 V
      const int ch  = mat*192 + g*64 + (col & 63);
      const u16* wrow = wq + ch*192 + kgrp*8;
      #pragma unroll
      for (int ks = 0; ks < 6; ++ks) {
        u16x8 bfr = *(const u16x8*)(wrow + ks*32);
        #pragma unroll
        for (int m = 0; m < 4; ++m) {
          u16x8 af = *(const u16x8*)&Xs[(m*16+arow)*200 + ks*32 + kgrp*8];
          acc[m] = mfma16(af, bfr, acc[m]);
        }
      }
      const float addb = qkvb[ch];
      if (mat == 2) {
        const int vc = col & 63;
        #pragma unroll
        for (int m = 0; m < 4; ++m) {
          u16x4 pk;
          #pragma unroll
          for (int r = 0; r < 4; ++r) pk[r] = f2bf(acc[m][r] + addb);
          *(u16x4*)&Vt[vc*72 + m*16 + kgrp*4] = pk;
        }
      } else {
        const float mult = (mat == 0) ? 0.17677669529663687f : 1.0f;
        const int gc = mat*64 + (col & 63);
        #pragma unroll
        for (int m = 0; m < 4; ++m)
          #pragma unroll
          for (int r = 0; r < 4; ++r)
            G[(m*16 + kgrp*4 + r)*136 + gc] = f2bf((acc[m][r] + addb)*mult);
      }
    }
    __syncthreads();

    // attention: one (hh,mt) task per wave
    const int hd = g*2 + hh;
    u16x8 qf = *(const u16x8*)&G[(mt*16+arow)*136 + hh*32 + kgrp*8];
    f32x4 sv[4];
    #pragma unroll
    for (int nt = 0; nt < 4; ++nt) {
      u16x8 kf = *(const u16x8*)&G[(nt*16+arow)*136 + 64 + hh*32 + kgrp*8];
      f32x4 z = {0,0,0,0};
      sv[nt] = mfma16(qf, kf, z);
    }
    // (no barrier: P scratch is private, G/Vt untouched until end-g barrier)

    int qj6[4];
    #pragma unroll
    for (int nt = 0; nt < 4; ++nt) {
      const int j = nt*16 + arow;
      qj6[nt] = ((j>>3)*15 + (j&7))*6;
    }
    float p[4][4];
    if (!boundary) {
      #pragma unroll
      for (int r = 0; r < 4; ++r) {
        const int i = mt*16 + kgrp*4 + r;
        const int qib = ((i>>3)*15 + (i&7) + 112)*6 + hd;
        #pragma unroll
        for (int nt = 0; nt < 4; ++nt)
          p[nt][r] = sv[nt][r] + (float)((int)biasQ[qib - qj6[nt]] - 128) * 0.0078125f;
      }
    } else {
      #pragma unroll
      for (int r = 0; r < 4; ++r) {
        const int i  = mt*16 + kgrp*4 + r;
        const int iy = i >> 3, ix = i & 7;
        const int qib = (iy*15 + ix + 112)*6 + hd;
        const int ri = ((wh==31) ? (iy<4?1:2) : 0)*3 + ((ww==31) ? (ix<4?1:2) : 0);
        #pragma unroll
        for (int nt = 0; nt < 4; ++nt) {
          const int j  = nt*16 + arow;
          const int jy = j >> 3, jx = j & 7;
          const int rj = ((wh==31) ? (jy<4?1:2) : 0)*3 + ((ww==31) ? (jx<4?1:2) : 0);
          float sc = sv[nt][r] + (float)((int)biasQ[qib - qj6[nt]] - 128) * 0.0078125f;
          if (ri != rj) sc -= 100.0f;
          p[nt][r] = sc;
        }
      }
    }
    // softmax without max-subtraction (|score| small; -100 mask underflows to 0)
    #pragma unroll
    for (int r = 0; r < 4; ++r) {
      float sum = 0.f;
      #pragma unroll
      for (int nt = 0; nt < 4; ++nt) { p[nt][r] = __expf(p[nt][r]); sum += p[nt][r]; }
      for (int off = 1; off < 16; off <<= 1) sum += __shfl_xor(sum, off, 64);
      const float inv = 1.0f / sum;
      #pragma unroll
      for (int nt = 0; nt < 4; ++nt) p[nt][r] *= inv;
    }
    // P -> col-rotated private per-wave scratch (row stride 72: bank-spread)
    u16* myP = Ps + wave*1152;
    #pragma unroll
    for (int r = 0; r < 4; ++r) {
      const int i = kgrp*4 + r;
      #pragma unroll
      for (int nt = 0; nt < 4; ++nt) {
        const int j = nt*16 + arow;
        myP[i*72 + ((j + 8*i) & 63)] = f2bf(p[nt][r]);
      }
    }
    f32x4 oacc[2] = {{0,0,0,0},{0,0,0,0}};
    #pragma unroll
    for (int ks = 0; ks < 2; ++ks) {
      u16x8 pf = *(const u16x8*)&myP[arow*72 + ((ks*32 + kgrp*8 + 8*arow) & 63)];
      #pragma unroll
      for (int nt = 0; nt < 2; ++nt) {
        u16x8 vf = *(const u16x8*)&Vt[(hh*32 + nt*16 + arow)*72 + ks*32 + kgrp*8];
        oacc[nt] = mfma16(pf, vf, oacc[nt]);
      }
    }
    #pragma unroll
    for (int nt = 0; nt < 2; ++nt)
      #pragma unroll
      for (int r = 0; r < 4; ++r)
        og[g][nt][r] = f2bf(oacc[nt][r]);
    __syncthreads();   // end-g: next QKV overwrites G/Vt
  }

  // ---- capture raw residual (tk8-rotated reads: 2-way banks) ----
  u16x8 rawreg[3];
  #pragma unroll
  for (int it = 0; it < 3; ++it) {
    const int id = it*512 + t;
    const int c = id >> 3, tk8 = (id & 7)*8;
    const int rot = id & 7;
    const float2 mi = stpR[c];
    u16x8 rr;
    #pragma unroll
    for (int k = 0; k < 8; ++k) {
      const int e = (k + rot) & 7;     // rotate by tk8/8: spreads row-blocks across banks
      float nv = bf2f(Xs[(tk8 + e)*200 + c]);
      rr[e] = f2bf(nv*mi.y + mi.x);
    }
    rawreg[it] = rr;
  }
  __syncthreads();

  // ---- O (regs) -> Xs ----
  #pragma unroll
  for (int g = 0; g < 3; ++g)
    #pragma unroll
    for (int nt = 0; nt < 2; ++nt) {
      const int colb = g*64 + hh*32 + nt*16 + arow;
      #pragma unroll
      for (int r = 0; r < 4; ++r)
        Xs[(mt*16 + kgrp*4 + r)*200 + colb] = og[g][nt][r];
    }
  __syncthreads();

  // ---- proj GEMM -> Pout [ch][tok] ----
  for (int nt0 = wave; nt0 < 12; nt0 += 8) {
    const int ch = nt0*16 + arow;
    const float pb = projb[ch];
    f32x4 acc[4];
    #pragma unroll
    for (int m = 0; m < 4; ++m) { f32x4 v = {pb,pb,pb,pb}; acc[m] = v; }
    const u16* wrow = wp + ch*192 + kgrp*8;
    #pragma unroll
    for (int ks = 0; ks < 6; ++ks) {
      u16x8 bfr = *(const u16x8*)(wrow + ks*32);
      #pragma unroll
      for (int m = 0; m < 4; ++m) {
        u16x8 af = *(const u16x8*)&Xs[(m*16+arow)*200 + ks*32 + kgrp*8];
        acc[m] = mfma16(af, bfr, acc[m]);
      }
    }
    #pragma unroll
    for (int m = 0; m < 4; ++m) {
      u16x4 pk;
      #pragma unroll
      for (int r = 0; r < 4; ++r) pk[r] = f2bf(acc[m][r]);
      *(u16x4*)&Pout[ch*72 + m*16 + kgrp*4] = pk;
    }
  }
  __syncthreads();

  // ---- epilogue: v = raw + proj -> pw [wid][c][64tok]; stats2 partials ----
  u16* dstw = pw + (long)wid*12288;
  #pragma unroll
  for (int it = 0; it < 3; ++it) {
    const int id = it*512 + t;
    const int c = id >> 3, tk8 = (id & 7)*8;
    u16x8 pv = *(const u16x8*)&Pout[c*72 + tk8];
    u16x8 rr = rawreg[it];
    u16x8 vb;
    float s = 0.f, q = 0.f;
    #pragma unroll
    for (int e = 0; e < 8; ++e) {
      float v = bf2f(rr[e]) + bf2f(pv[e]);
      vb[e] = f2bf(v);
      s += v; q += v*v;
    }
    *(u16x8*)(dstw + c*64 + tk8) = vb;
    s += __shfl_xor(s, 1, 64); q += __shfl_xor(q, 1, 64);
    s += __shfl_xor(s, 2, 64); q += __shfl_xor(q, 2, 64);
    s += __shfl_xor(s, 4, 64); q += __shfl_xor(q, 4, 64);
    if ((lane & 7) == 0) {
      float2 pr = {s, q};
      part[(long)wid*192 + c] = pr;
    }
  }
}

// ---- stats2: reduce per-window v partials -> (mean, rstd) ----
__global__ __launch_bounds__(256) void stats2_kernel(
    const float2* __restrict__ part, float2* __restrict__ st2f) {
  const int b = blockIdx.x / 12, cg = blockIdx.x % 12;
  const int cl = threadIdx.x & 15;
  const int w0 = threadIdx.x >> 4;
  const int c = cg*16 + cl;
  float s = 0.f, q = 0.f;
  for (int w = w0; w < 1024; w += 16) {
    float2 v = part[((long)(b*1024 + w))*192 + c];
    s += v.x; q += v.y;
  }
  s += __shfl_xor(s, 16, 64); q += __shfl_xor(q, 16, 64);
  s += __shfl_xor(s, 32, 64); q += __shfl_xor(q, 32, 64);
  __shared__ float2 aux[4][16];
  if ((threadIdx.x & 63) < 16) { float2 v = {s, q}; aux[threadIdx.x >> 6][cl] = v; }
  __syncthreads();
  if (threadIdx.x < 16) {
    float2 a0 = aux[0][cl], a1 = aux[1][cl], a2 = aux[2][cl], a3 = aux[3][cl];
    float S = a0.x + a1.x + a2.x + a3.x;
    float Q = a0.y + a1.y + a2.y + a3.y;
    float mean = S * (1.f/PLANE);
    float var  = Q * (1.f/PLANE) - mean*mean;
    float2 o = {mean, rsqrtf(var + 1e-5f)};
    st2f[b*192 + c] = o;
  }
}

// ---- final: out = v + FiLM(norm2(v)); one block per (b, wh-band, c-chunk) ----
__global__ __launch_bounds__(256) void final_kernel(
    const u16* __restrict__ pw, const float2* __restrict__ st2f,
    const float* __restrict__ gb, float* __restrict__ out)
{
  __shared__ u16 tile[32*264];
  const int t = threadIdx.x;
  const int bid = blockIdx.x;
  const int lin = (bid & 7)*96 + (bid >> 3);   // 768 blocks, XCD-contiguous
  const int cc = lin % 6;
  const int band = lin / 6;                    // 0..127
  const int wh = band & 31;
  const int b  = band >> 5;
  const int c0 = cc*32;

  const int ww = t >> 3, cq = t & 7;
  const long wid = b*1024 + wh*32 + ww;
  const u16* srcw = pw + wid*12288;
  const int g1 = ww*8 + 4, g2 = (ww*8 + 8) & 255;

  const int cl = t >> 3, seg = t & 7;
  const int c = c0 + cl;
  const float2 mr = st2f[b*192 + c];
  const float mean = mr.x, rstd = mr.y;
  const float gmm  = gb[b*384 + c];
  const float be   = gb[b*384 + 192 + c];
  const int swb = (cl & 7) << 2;

  for (int ay = 0; ay < 8; ++ay) {
    #pragma unroll
    for (int j = 0; j < 4; ++j) {
      const int ca = cq*4 + j;
      u16x8 v = *(const u16x8*)(srcw + (c0+ca)*64 + ay*8);
      const int sw = (ca & 7) << 2;
      u16x4 lo = {v[0],v[1],v[2],v[3]}, hi = {v[4],v[5],v[6],v[7]};
      *(u16x4*)&tile[ca*264 + (g1 ^ sw)] = lo;
      *(u16x4*)&tile[ca*264 + (g2 ^ sw)] = hi;
    }
    __syncthreads();

    const int gy = (wh*8 + ay + 4) & 255;
    const long base = (((long)(b*192 + c)) << 16) + gy*256 + seg*32;
    float* orow = out + base;
    #pragma unroll
    for (int q4 = 0; q4 < 32; q4 += 4) {
      const int px = seg*32 + q4;
      u16x4 pv = *(const u16x4*)&tile[cl*264 + (px ^ swb)];
      float4 o;
      float v0 = bf2f(pv[0]), v1 = bf2f(pv[1]), v2 = bf2f(pv[2]), v3 = bf2f(pv[3]);
      o.x = v0 + (v0 - mean)*rstd*gmm + be;
      o.y = v1 + (v1 - mean)*rstd*gmm + be;
      o.z = v2 + (v2 - mean)*rstd*gmm + be;
      o.w = v3 + (v3 - mean)*rstd*gmm + be;
      *(float4*)(orow + q4) = o;
    }
    __syncthreads();
  }
}

extern "C" void kernel_launch(void* const* d_in, const int* in_sizes, int n_in,
                              void* d_out, int out_size, void* d_ws, size_t ws_size,
                              hipStream_t stream) {
  const float* x      = (const float*)d_in[0];
  const float* cond   = (const float*)d_in[1];
  const float* qkv_w  = (const float*)d_in[2];
  const float* qkv_b  = (const float*)d_in[3];
  const float* proj_w = (const float*)d_in[4];
  const float* proj_b = (const float*)d_in[5];
  const float* relb   = (const float*)d_in[6];
  const float* film_w = (const float*)d_in[7];
  const float* film_b = (const float*)d_in[8];
  float* out = (float*)d_out;

  char* ws = (char*)d_ws;
  float*  stats1 = (float*)ws;                        // 768*2 f32
  float2* st2f   = (float2*)(ws + 6144);              // 768 float2
  float*  gb     = (float*)(ws + 12288);              // 4*384 f32
  u16*    wq     = (u16*)(ws + 18432);                // 576*192 bf16
  u16*    wp     = (u16*)(ws + 239616);               // 192*192 bf16
  u8*     bqq    = (u8*)(ws + 313344);                // 1350 u8
  u16*    xbuf   = (u16*)(ws + 362496);               // 4096*64*192 bf16 (raw xn -> v)
  float2* part   = (float2*)(ws + 362496 + 100663296);// 4096*192 float2
  float2* part1  = (float2*)(ws + 362496 + 100663296 + 6291456); // 4*32*6*32 float2

  prep_kernel<<<768, 256, 0, stream>>>(x, xbuf, part1);
  setup_kernel<<<441, 256, 0, stream>>>(qkv_w, proj_w, relb, cond, film_w, film_b,
                                        part1, wq, wp, bqq, gb, stats1);
  attn_kernel<<<4096, 512, 0, stream>>>(xbuf, wq, wp, qkv_b, proj_b, bqq, stats1, xbuf, part);
  stats2_kernel<<<48, 256, 0, stream>>>(part, st2f);
  final_kernel<<<768, 256, 0, stream>>>(xbuf, st2f, gb, out);
}

// Round 23
// 470.163 us; speedup vs baseline: 1.0160x; 1.0027x over previous
//
#include <hip/hip_runtime.h>

#define BATCH 4
#define CH    192
#define PLANE 65536

typedef unsigned short u16;
typedef unsigned char  u8;
typedef __bf16 bf16x8_t __attribute__((ext_vector_type(8)));
typedef unsigned short u16x8 __attribute__((ext_vector_type(8)));
typedef unsigned short u16x4 __attribute__((ext_vector_type(4)));
typedef float f32x4 __attribute__((ext_vector_type(4)));

__device__ __forceinline__ u16 f2bf(float f) {
  __bf16 h = (__bf16)f;
  return __builtin_bit_cast(u16, h);
}
__device__ __forceinline__ float bf2f(u16 h) {
  unsigned u = ((unsigned)h) << 16;
  return __builtin_bit_cast(float, u);
}
__device__ __forceinline__ f32x4 mfma16(u16x8 a, u16x8 b, f32x4 c) {
  return __builtin_amdgcn_mfma_f32_16x16x32_bf16(
      __builtin_bit_cast(bf16x8_t, a), __builtin_bit_cast(bf16x8_t, b), c, 0, 0, 0);
}

// ---- prep: window-partition raw x -> bf16 [wid][tok][192c] + stats1 partials ----
__global__ __launch_bounds__(256) void prep_kernel(
    const float* __restrict__ x, u16* __restrict__ xraw, float2* __restrict__ part1)
{
  __shared__ u16 tile[32*264];
  const int t = threadIdx.x;
  const int bid = blockIdx.x;
  const int cc = bid % 6;
  const int wh = (bid/6) % 32;
  const int b  = bid / 192;
  const int c0 = cc*32;
  const int ww = t >> 3, ax = t & 7;
  const int gx = (ww*8 + ax + 4) & 255;
  const int gxb = gx & ~3, gxr = gx & 3;
  const long wid = b*1024 + wh*32 + ww;

  const int scl = t >> 3, sseg = t & 7;
  float myS = 0.f, myQ = 0.f;

  for (int ay = 0; ay < 8; ++ay) {
    const int gy = (wh*8 + ay + 4) & 255;
    for (int it = 0; it < 8; ++it) {
      const int id = it*256 + t;
      const int cl = id >> 6;
      const int px = (id & 63) << 2;
      float4 v = *(const float4*)(x + (((long)(b*192+c0+cl)) << 16) + gy*256 + px);
      u16x4 pk;
      pk[0] = f2bf(v.x); pk[1] = f2bf(v.y); pk[2] = f2bf(v.z); pk[3] = f2bf(v.w);
      *(u16x4*)&tile[cl*264 + (px ^ ((cl&7)<<2))] = pk;
    }
    __syncthreads();
    {
      const int sw = (scl & 7) << 2;
      #pragma unroll
      for (int k = 0; k < 32; k += 4) {
        const int px = sseg*32 + k;
        u16x4 pv = *(const u16x4*)&tile[scl*264 + (px ^ sw)];
        float a0 = bf2f(pv[0]), a1 = bf2f(pv[1]), a2 = bf2f(pv[2]), a3 = bf2f(pv[3]);
        myS += a0 + a1 + a2 + a3;
        myQ += a0*a0 + a1*a1 + a2*a2 + a3*a3;
      }
    }
    u16* dst = xraw + wid*12288 + (ay*8+ax)*192 + c0;
    #pragma unroll
    for (int k = 0; k < 4; ++k) {
      u16x8 pk;
      #pragma unroll
      for (int e = 0; e < 8; ++e) {
        const int c = k*8 + e;
        pk[e] = tile[c*264 + (gxb ^ ((c&7)<<2)) + gxr];
      }
      *(u16x8*)(dst + k*8) = pk;
    }
    __syncthreads();
  }
  for (int off = 1; off < 8; off <<= 1) {
    myS += __shfl_xor(myS, off, 64);
    myQ += __shfl_xor(myQ, off, 64);
  }
  if (sseg == 0) {
    float2 pr = {myS, myQ};
    part1[((b*32 + wh)*6 + cc)*32 + scl] = pr;
  }
}

// ---- setup: weights->bf16, bias->bf16, gamma/beta, statsR — one kernel ----
__global__ __launch_bounds__(256) void setup_kernel(
    const float* __restrict__ a, const float* __restrict__ b2,
    const float* __restrict__ rb, const float* __restrict__ cond,
    const float* __restrict__ fw, const float* __restrict__ fb,
    const float2* __restrict__ part1,
    u16* __restrict__ wa, u16* __restrict__ wb, u16* __restrict__ bq,
    float* __restrict__ gb, float* __restrict__ st)
{
  const int blk = blockIdx.x;
  if (blk < 432) {
    const int i = blk*256 + threadIdx.x;
    if (i < 576*192) wa[i] = f2bf(a[i]);
    if (i < 192*192) wb[i] = f2bf(b2[i]);
    if (i < 1350) bq[i] = f2bf(rb[i]);
  } else if (blk < 438) {
    const int i = (blk - 432)*256 + threadIdx.x;
    if (i >= BATCH*384) return;
    const int bb = i / 384, oc = i - bb*384;
    const float* cw = fw + oc*128;
    const float* cv = cond + bb*128;
    float s = fb[oc];
    for (int k = 0; k < 128; ++k) s += cv[k]*cw[k];
    gb[i] = s;
  } else {
    const int i = (blk - 438)*256 + threadIdx.x;
    if (i >= 768) return;
    const int b = i / 192, c = i % 192;
    const int cg = c >> 5, cl = c & 31;
    float s = 0.f, q = 0.f;
    for (int wh = 0; wh < 32; ++wh) {
      float2 v = part1[((b*32 + wh)*6 + cg)*32 + cl];
      s += v.x; q += v.y;
    }
    const float mean = s * (1.f/PLANE);
    const float var  = q * (1.f/PLANE) - mean*mean;
    st[i*2]   = mean;
    st[i*2+1] = rsqrtf(var + 1e-5f);
  }
}

// ---- fused window attention + residual epilogue ----
// LDS: Xs [64][200] @0 (25600)        normalized X, later O
//      G  [64][136] @25600 (17408)    Q|K
//      Vt [64][72]  @43008 (9216)
//      Pout [192][72] @25600 (27648, aliases G+Vt after attention)
//      biasB u16[1350] @52224 (2700)  bf16 rel-bias table
//      stpNp float2[216] @54928 (1728) (mean, rstd) PADDED: idx = c + (c>>3)
//      stpR float2[192] @56656 (1536)  (mean, 1/rstd)
//      Ps  u16[8][16*72] @58192 (18432) private per-wave P scratch, stride 72
__global__ __launch_bounds__(512, 4) void attn_kernel(
    const u16* __restrict__ xn, const u16* __restrict__ wq, const u16* __restrict__ wp,
    const float* __restrict__ qkvb, const float* __restrict__ projb,
    const u16* __restrict__ bq, const float* __restrict__ st,
    u16* __restrict__ pw, float2* __restrict__ part)
{
  __shared__ __attribute__((aligned(16))) unsigned char smem[76624];
  u16*    Xs    = (u16*)smem;
  u16*    G     = (u16*)(smem + 25600);
  u16*    Vt    = (u16*)(smem + 43008);
  u16*    Pout  = (u16*)(smem + 25600);
  u16*    biasB = (u16*)(smem + 52224);
  float2* stpNp = (float2*)(smem + 54928);
  float2* stpR  = (float2*)(smem + 56656);
  u16*    Ps    = (u16*)(smem + 58192);

  const int t    = threadIdx.x;
  const int lane = t & 63;
  const int wave = t >> 6;
  const int arow = lane & 15;
  const int kgrp = lane >> 4;

  const int bid = blockIdx.x;
  const int wid = (bid & 7) * 512 + (bid >> 3);   // XCD-contiguous
  const int b   = wid >> 10;
  const int wh  = (wid >> 5) & 31;
  const int ww  = wid & 31;

  // ---- tables first (stage depends on stpNp) ----
  for (int i = t; i < 1350; i += 512) biasB[i] = bq[i];
  if (t < 192) {
    const float mean = st[(b*192 + t)*2];
    const float rstd = st[(b*192 + t)*2 + 1];
    float2 n = {mean, rstd};
    float2 r = {mean, 1.0f / rstd};
    stpNp[t + (t >> 3)] = n;   // padded: bank-spread reads in stage
    stpR[t] = r;
  }
  __syncthreads();

  // ---- stage: raw bf16 copy + normalize -> Xs ----
  const u16* src = xn + (long)wid*12288;
  #pragma unroll
  for (int it = 0; it < 3; ++it) {
    const int id = it*512 + t;
    const int row = id/24, c8 = (id%24)*8;
    const int sbase = c8 + (c8 >> 3);
    u16x8 raw = *(const u16x8*)(src + id*8);
    u16x8 nrm;
    #pragma unroll
    for (int e = 0; e < 8; ++e) {
      float2 mr = stpNp[sbase + e];
      nrm[e] = f2bf((bf2f(raw[e]) - mr.x) * mr.y);
    }
    *(u16x8*)&Xs[row*200 + c8] = nrm;
  }
  __syncthreads();

  const int hh = wave >> 2;
  const int mt = wave & 3;
  const bool boundary = (wh == 31) || (ww == 31);
  u16x4 og[3][2];

  #pragma unroll
  for (int g = 0; g < 3; ++g) {
    // QKV slice GEMM: 12 ntiles over 8 waves
    for (int nt0 = wave; nt0 < 12; nt0 += 8) {
      f32x4 acc[4] = {{0,0,0,0},{0,0,0,0},{0,0,0,0},{0,0,0,0}};
      const int col = nt0*16 + arow;
      const int mat = col >> 6;                 // 0 Q, 1 K, 2 V
      const int ch  = mat*192 + g*64 + (col & 63);
      const u16* wrow = wq + ch*192 + kgrp*8;
      #pragma unroll
      for (int ks = 0; ks < 6; ++ks) {
        u16x8 bfr = *(const u16x8*)(wrow + ks*32);
        #pragma unroll
        for (int m = 0; m < 4; ++m) {
          u16x8 af = *(const u16x8*)&Xs[(m*16+arow)*200 + ks*32 + kgrp*8];
          acc[m] = mfma16(af, bfr, acc[m]);
        }
      }
      const float addb = qkvb[ch];
      if (mat == 2) {
        const int vc = col & 63;
        #pragma unroll
        for (int m = 0; m < 4; ++m) {
          u16x4 pk;
          #pragma unroll
          for (int r = 0; r < 4; ++r) pk[r] = f2bf(acc[m][r] + addb);
          *(u16x4*)&Vt[vc*72 + m*16 + kgrp*4] = pk;
        }
      } else {
        const float mult = (mat == 0) ? 0.17677669529663687f : 1.0f;
        const int gc = mat*64 + (col & 63);
        #pragma unroll
        for (int m = 0; m < 4; ++m)
          #pragma unroll
          for (int r = 0; r < 4; ++r)
            G[(m*16 + kgrp*4 + r)*136 + gc] = f2bf((acc[m][r] + addb)*mult);
      }
    }
    __syncthreads();

    // attention: one (hh,mt) task per wave
    const int hd = g*2 + hh;
    u16x8 qf = *(const u16x8*)&G[(mt*16+arow)*136 + hh*32 + kgrp*8];
    f32x4 sv[4];
    #pragma unroll
    for (int nt = 0; nt < 4; ++nt) {
      u16x8 kf = *(const u16x8*)&G[(nt*16+arow)*136 + 64 + hh*32 + kgrp*8];
      f32x4 z = {0,0,0,0};
      sv[nt] = mfma16(qf, kf, z);
    }
    // (no barrier: P scratch is private, G/Vt untouched until end-g barrier)

    int qj6[4];
    #pragma unroll
    for (int nt = 0; nt < 4; ++nt) {
      const int j = nt*16 + arow;
      qj6[nt] = ((j>>3)*15 + (j&7))*6;
    }
    float p[4][4];
    if (!boundary) {
      #pragma unroll
      for (int r = 0; r < 4; ++r) {
        const int i = mt*16 + kgrp*4 + r;
        const int qib = ((i>>3)*15 + (i&7) + 112)*6 + hd;
        #pragma unroll
        for (int nt = 0; nt < 4; ++nt)
          p[nt][r] = sv[nt][r] + bf2f(biasB[qib - qj6[nt]]);
      }
    } else {
      #pragma unroll
      for (int r = 0; r < 4; ++r) {
        const int i  = mt*16 + kgrp*4 + r;
        const int iy = i >> 3, ix = i & 7;
        const int qib = (iy*15 + ix + 112)*6 + hd;
        const int ri = ((wh==31) ? (iy<4?1:2) : 0)*3 + ((ww==31) ? (ix<4?1:2) : 0);
        #pragma unroll
        for (int nt = 0; nt < 4; ++nt) {
          const int j  = nt*16 + arow;
          const int jy = j >> 3, jx = j & 7;
          const int rj = ((wh==31) ? (jy<4?1:2) : 0)*3 + ((ww==31) ? (jx<4?1:2) : 0);
          float sc = sv[nt][r] + bf2f(biasB[qib - qj6[nt]]);
          if (ri != rj) sc -= 100.0f;
          p[nt][r] = sc;
        }
      }
    }
    // softmax without max-subtraction (|score| small; -100 mask underflows to 0)
    #pragma unroll
    for (int r = 0; r < 4; ++r) {
      float sum = 0.f;
      #pragma unroll
      for (int nt = 0; nt < 4; ++nt) { p[nt][r] = __expf(p[nt][r]); sum += p[nt][r]; }
      for (int off = 1; off < 16; off <<= 1) sum += __shfl_xor(sum, off, 64);
      const float inv = 1.0f / sum;
      #pragma unroll
      for (int nt = 0; nt < 4; ++nt) p[nt][r] *= inv;
    }
    // P -> col-rotated private per-wave scratch (row stride 72: bank-spread)
    u16* myP = Ps + wave*1152;
    #pragma unroll
    for (int r = 0; r < 4; ++r) {
      const int i = kgrp*4 + r;
      #pragma unroll
      for (int nt = 0; nt < 4; ++nt) {
        const int j = nt*16 + arow;
        myP[i*72 + ((j + 8*i) & 63)] = f2bf(p[nt][r]);
      }
    }
    f32x4 oacc[2] = {{0,0,0,0},{0,0,0,0}};
    #pragma unroll
    for (int ks = 0; ks < 2; ++ks) {
      u16x8 pf = *(const u16x8*)&myP[arow*72 + ((ks*32 + kgrp*8 + 8*arow) & 63)];
      #pragma unroll
      for (int nt = 0; nt < 2; ++nt) {
        u16x8 vf = *(const u16x8*)&Vt[(hh*32 + nt*16 + arow)*72 + ks*32 + kgrp*8];
        oacc[nt] = mfma16(pf, vf, oacc[nt]);
      }
    }
    #pragma unroll
    for (int nt = 0; nt < 2; ++nt)
      #pragma unroll
      for (int r = 0; r < 4; ++r)
        og[g][nt][r] = f2bf(oacc[nt][r]);
    __syncthreads();   // end-g: next QKV overwrites G/Vt
  }

  // ---- capture raw residual (epilogue lane mapping) before O overwrites Xs ----
  u16x8 rawreg[3];
  #pragma unroll
  for (int it = 0; it < 3; ++it) {
    const int id = it*512 + t;
    const int c = id >> 3, tk8 = (id & 7)*8;
    const float2 mi = stpR[c];
    u16x8 rr;
    #pragma unroll
    for (int e = 0; e < 8; ++e) {
      float nv = bf2f(Xs[(tk8 + e)*200 + c]);
      rr[e] = f2bf(nv*mi.y + mi.x);
    }
    rawreg[it] = rr;
  }
  __syncthreads();

  // ---- O (regs) -> Xs ----
  #pragma unroll
  for (int g = 0; g < 3; ++g)
    #pragma unroll
    for (int nt = 0; nt < 2; ++nt) {
      const int colb = g*64 + hh*32 + nt*16 + arow;
      #pragma unroll
      for (int r = 0; r < 4; ++r)
        Xs[(mt*16 + kgrp*4 + r)*200 + colb] = og[g][nt][r];
    }
  __syncthreads();

  // ---- proj GEMM -> Pout [ch][tok] ----
  for (int nt0 = wave; nt0 < 12; nt0 += 8) {
    const int ch = nt0*16 + arow;
    const float pb = projb[ch];
    f32x4 acc[4];
    #pragma unroll
    for (int m = 0; m < 4; ++m) { f32x4 v = {pb,pb,pb,pb}; acc[m] = v; }
    const u16* wrow = wp + ch*192 + kgrp*8;
    #pragma unroll
    for (int ks = 0; ks < 6; ++ks) {
      u16x8 bfr = *(const u16x8*)(wrow + ks*32);
      #pragma unroll
      for (int m = 0; m < 4; ++m) {
        u16x8 af = *(const u16x8*)&Xs[(m*16+arow)*200 + ks*32 + kgrp*8];
        acc[m] = mfma16(af, bfr, acc[m]);
      }
    }
    #pragma unroll
    for (int m = 0; m < 4; ++m) {
      u16x4 pk;
      #pragma unroll
      for (int r = 0; r < 4; ++r) pk[r] = f2bf(acc[m][r]);
      *(u16x4*)&Pout[ch*72 + m*16 + kgrp*4] = pk;
    }
  }
  __syncthreads();

  // ---- epilogue: v = raw + proj -> pw [wid][c][64tok]; stats2 partials ----
  u16* dstw = pw + (long)wid*12288;
  #pragma unroll
  for (int it = 0; it < 3; ++it) {
    const int id = it*512 + t;
    const int c = id >> 3, tk8 = (id & 7)*8;
    u16x8 pv = *(const u16x8*)&Pout[c*72 + tk8];
    u16x8 rr = rawreg[it];
    u16x8 vb;
    float s = 0.f, q = 0.f;
    #pragma unroll
    for (int e = 0; e < 8; ++e) {
      float v = bf2f(rr[e]) + bf2f(pv[e]);
      vb[e] = f2bf(v);
      s += v; q += v*v;
    }
    *(u16x8*)(dstw + c*64 + tk8) = vb;
    s += __shfl_xor(s, 1, 64); q += __shfl_xor(q, 1, 64);
    s += __shfl_xor(s, 2, 64); q += __shfl_xor(q, 2, 64);
    s += __shfl_xor(s, 4, 64); q += __shfl_xor(q, 4, 64);
    if ((lane & 7) == 0) {
      float2 pr = {s, q};
      part[(long)wid*192 + c] = pr;
    }
  }
}

// ---- stats2: reduce per-window v partials -> (mean, rstd) ----
__global__ __launch_bounds__(256) void stats2_kernel(
    const float2* __restrict__ part, float2* __restrict__ st2f) {
  const int b = blockIdx.x / 12, cg = blockIdx.x % 12;
  const int cl = threadIdx.x & 15;
  const int w0 = threadIdx.x >> 4;
  const int c = cg*16 + cl;
  float s = 0.f, q = 0.f;
  for (int w = w0; w < 1024; w += 16) {
    float2 v = part[((long)(b*1024 + w))*192 + c];
    s += v.x; q += v.y;
  }
  s += __shfl_xor(s, 16, 64); q += __shfl_xor(q, 16, 64);
  s += __shfl_xor(s, 32, 64); q += __shfl_xor(q, 32, 64);
  __shared__ float2 aux[4][16];
  if ((threadIdx.x & 63) < 16) { float2 v = {s, q}; aux[threadIdx.x >> 6][cl] = v; }
  __syncthreads();
  if (threadIdx.x < 16) {
    float2 a0 = aux[0][cl], a1 = aux[1][cl], a2 = aux[2][cl], a3 = aux[3][cl];
    float S = a0.x + a1.x + a2.x + a3.x;
    float Q = a0.y + a1.y + a2.y + a3.y;
    float mean = S * (1.f/PLANE);
    float var  = Q * (1.f/PLANE) - mean*mean;
    float2 o = {mean, rsqrtf(var + 1e-5f)};
    st2f[b*192 + c] = o;
  }
}

// ---- final: out = v + FiLM(norm2(v)); one block per (b, wh-band, c-chunk) ----
__global__ __launch_bounds__(256) void final_kernel(
    const u16* __restrict__ pw, const float2* __restrict__ st2f,
    const float* __restrict__ gb, float* __restrict__ out)
{
  __shared__ u16 tile[32*264];
  const int t = threadIdx.x;
  const int bid = blockIdx.x;
  const int lin = (bid & 7)*96 + (bid >> 3);   // 768 blocks, XCD-contiguous
  const int cc = lin % 6;
  const int band = lin / 6;                    // 0..127
  const int wh = band & 31;
  const int b  = band >> 5;
  const int c0 = cc*32;

  const int ww = t >> 3, cq = t & 7;
  const long wid = b*1024 + wh*32 + ww;
  const u16* srcw = pw + wid*12288;
  const int g1 = ww*8 + 4, g2 = (ww*8 + 8) & 255;

  const int cl = t >> 3, seg = t & 7;
  const int c = c0 + cl;
  const float2 mr = st2f[b*192 + c];
  const float mean = mr.x, rstd = mr.y;
  const float gmm  = gb[b*384 + c];
  const float be   = gb[b*384 + 192 + c];
  const int swb = (cl & 7) << 2;

  for (int ay = 0; ay < 8; ++ay) {
    #pragma unroll
    for (int j = 0; j < 4; ++j) {
      const int ca = cq*4 + j;
      u16x8 v = *(const u16x8*)(srcw + (c0+ca)*64 + ay*8);
      const int sw = (ca & 7) << 2;
      u16x4 lo = {v[0],v[1],v[2],v[3]}, hi = {v[4],v[5],v[6],v[7]};
      *(u16x4*)&tile[ca*264 + (g1 ^ sw)] = lo;
      *(u16x4*)&tile[ca*264 + (g2 ^ sw)] = hi;
    }
    __syncthreads();

    const int gy = (wh*8 + ay + 4) & 255;
    const long base = (((long)(b*192 + c)) << 16) + gy*256 + seg*32;
    float* orow = out + base;
    #pragma unroll
    for (int q4 = 0; q4 < 32; q4 += 4) {
      const int px = seg*32 + q4;
      u16x4 pv = *(const u16x4*)&tile[cl*264 + (px ^ swb)];
      float4 o;
      float v0 = bf2f(pv[0]), v1 = bf2f(pv[1]), v2 = bf2f(pv[2]), v3 = bf2f(pv[3]);
      o.x = v0 + (v0 - mean)*rstd*gmm + be;
      o.y = v1 + (v1 - mean)*rstd*gmm + be;
      o.z = v2 + (v2 - mean)*rstd*gmm + be;
      o.w = v3 + (v3 - mean)*rstd*gmm + be;
      *(float4*)(orow + q4) = o;
    }
    __syncthreads();
  }
}

extern "C" void kernel_launch(void* const* d_in, const int* in_sizes, int n_in,
                              void* d_out, int out_size, void* d_ws, size_t ws_size,
                              hipStream_t stream) {
  const float* x      = (const float*)d_in[0];
  const float* cond   = (const float*)d_in[1];
  const float* qkv_w  = (const float*)d_in[2];
  const float* qkv_b  = (const float*)d_in[3];
  const float* proj_w = (const float*)d_in[4];
  const float* proj_b = (const float*)d_in[5];
  const float* relb   = (const float*)d_in[6];
  const float* film_w = (const float*)d_in[7];
  const float* film_b = (const float*)d_in[8];
  float* out = (float*)d_out;

  char* ws = (char*)d_ws;
  float*  stats1 = (float*)ws;                        // 768*2 f32
  float2* st2f   = (float2*)(ws + 6144);              // 768 float2
  float*  gb     = (float*)(ws + 12288);              // 4*384 f32
  u16*    wq     = (u16*)(ws + 18432);                // 576*192 bf16
  u16*    wp     = (u16*)(ws + 239616);               // 192*192 bf16
  u16*    bqq    = (u16*)(ws + 313344);               // 1350 bf16
  u16*    xbuf   = (u16*)(ws + 362496);               // 4096*64*192 bf16 (raw xn -> v)
  float2* part   = (float2*)(ws + 362496 + 100663296);// 4096*192 float2
  float2* part1  = (float2*)(ws + 362496 + 100663296 + 6291456); // 4*32*6*32 float2

  prep_kernel<<<768, 256, 0, stream>>>(x, xbuf, part1);
  setup_kernel<<<441, 256, 0, stream>>>(qkv_w, proj_w, relb, cond, film_w, film_b,
                                        part1, wq, wp, bqq, gb, stats1);
  attn_kernel<<<4096, 512, 0, stream>>>(xbuf, wq, wp, qkv_b, proj_b, bqq, stats1, xbuf, part);
  stats2_kernel<<<48, 256, 0, stream>>>(part, st2f);
  final_kernel<<<768, 256, 0, stream>>>(xbuf, st2f, gb, out);
}